// Round 9
// baseline (4245.985 us; speedup 1.0000x reference)
//
#include <hip/hip_runtime.h>
#include <hip/hip_fp16.h>
#include <math.h>

#define B_ 32
#define S_ 1024
#define D_ 768
#define L_ 12
#define SD 786432LL      // S_*D_ halves per batch
#define SS 1048576LL     // S_*S_ halves per batch
#define DD 589824LL      // D_*D_
#define LDL 1769472LL    // 3*DD halves per layer of Wcat (2304 x 768)

typedef _Float16 half8 __attribute__((ext_vector_type(8)));
typedef float f32x4 __attribute__((ext_vector_type(4)));
typedef unsigned short u16;

// chunk swizzle for the 128^2 att epilogue LDS bounce
#define SW(lr) ((((lr) ^ ((lr) >> 3)) & 7))
// chunk swizzle key for the 256x128 QKV epilogue bounce (round-6 verified)
#define KEY16(r) (((r) ^ ((r) >> 3)) & 15)

// global_load_lds, width 16
#define GLD16(p, o) __builtin_amdgcn_global_load_lds( \
        (const __attribute__((address_space(1))) void*)(p), \
        (__attribute__((address_space(3))) void*)&smem[o], 16, 0, 0)

// ===========================================================================
// Fused QKV projection — ROUND-6 PROVEN FORM (146 us, VGPR 124, no spill)
// + T5 setprio around the MFMA cluster (round-9). 256x128 tile, 4 waves
// (2M x 2N), wave-tile 128x64, acc[8][4]. 3-slot ring (A @ s*12288 8192 u16,
// B +8192; 72 KB), depth-2 prefetch, fused counted gate
// [s_waitcnt vmcnt(6); s_barrier]. 2 blocks/CU.
// setprio mechanism: the 2 co-resident blocks share no barrier -> their
// waves sit at different slice phases; priority(1) during the MFMA cluster
// wins issue arbitration vs the other block's staging waves (m191/m218b
// regime, NOT the m190 lockstep null).
// NOTE (round-7 lesson): acc[8][4] ~> 256 VGPR/wave; __launch_bounds__(256,3)
// spills accumulators to scratch (9x HBM write amplification, 3.8x slower).
// ===========================================================================
template<int SWIZ>
__global__ __launch_bounds__(256, 2)
void gemm_qkv_k(const __half* __restrict__ A, const __half* __restrict__ Wt,
                const float* __restrict__ biasC, const float* __restrict__ scaleC,
                float aBias,
                __half* __restrict__ CQ, __half* __restrict__ CK, __half* __restrict__ CVt,
                int nBase, int tilesX, int mPerXcd)
{
    __shared__ __align__(16) u16 smem[36864];   // 72 KB ring; 64 KB bounce reuse
    const int K = 768;

    int mIdx, nxI;
    if (SWIZ) {
        const int flat = blockIdx.x;
        const int xcd = flat & 7;
        const int jj = flat >> 3;
        const int mLocal = jj / tilesX;
        nxI = jj - mLocal * tilesX;
        mIdx = xcd * mPerXcd + mLocal;
    } else {
        mIdx = blockIdx.x / tilesX;
        nxI = blockIdx.x - mIdx * tilesX;
    }
    const int m0 = mIdx * 256;
    const int n0 = nxI * 128;

    const int t = threadIdx.x;
    const int l = t & 63, w = t >> 6;
    const int wm = (w & 1) * 128, wn = (w >> 1) * 64;
    const int q = l >> 4, lr = l & 15;

    // staging: A slice 256x32 = 1024 16B-chunks (4/thread), B 128x32 = 512
    // (2/thread). LDS linear in chunk index; global k-chunk pre-swizzled.
    const int uA0 = t, uA1 = t + 256, uA2 = t + 512, uA3 = t + 768;
    const int uB0 = t, uB1 = t + 256;
#define MKA(u) (A + (long long)(m0 + ((u) >> 2)) * K + ((((u) & 3) ^ ((((u) >> 2) >> 1) & 3)) * 8))
#define MKB(u) (Wt + (long long)(n0 + ((u) >> 2)) * K + ((((u) & 3) ^ ((((u) >> 2) >> 1) & 3)) * 8))
    const __half* gA0 = MKA(uA0); const __half* gA1 = MKA(uA1);
    const __half* gA2 = MKA(uA2); const __half* gA3 = MKA(uA3);
    const __half* gB0 = MKB(uB0); const __half* gB1 = MKB(uB1);
#undef MKA
#undef MKB

    int aoff[8], boff[4];
    #pragma unroll
    for (int mf = 0; mf < 8; ++mf) {
        int rr = wm + mf * 16 + lr;
        aoff[mf] = (rr * 4 + (q ^ ((rr >> 1) & 3))) * 8;
    }
    #pragma unroll
    for (int nf = 0; nf < 4; ++nf) {
        int rb = wn + nf * 16 + lr;
        boff[nf] = (rb * 4 + (q ^ ((rb >> 1) & 3))) * 8;
    }

    f32x4 acc[8][4];
    #pragma unroll
    for (int i = 0; i < 8; ++i)
        #pragma unroll
        for (int j = 0; j < 4; ++j)
            acc[i][j] = (f32x4){0.f, 0.f, 0.f, 0.f};

    // prologue: slice 0 -> slot 0, slice 1 -> slot 1 (12 loads, issue order!)
    GLD16(gA0, uA0 * 8); GLD16(gA1, uA1 * 8); GLD16(gA2, uA2 * 8); GLD16(gA3, uA3 * 8);
    GLD16(gB0, 8192 + uB0 * 8); GLD16(gB1, 8192 + uB1 * 8);
    GLD16(gA0 + 32, 12288 + uA0 * 8); GLD16(gA1 + 32, 12288 + uA1 * 8);
    GLD16(gA2 + 32, 12288 + uA2 * 8); GLD16(gA3 + 32, 12288 + uA3 * 8);
    GLD16(gB0 + 32, 12288 + 8192 + uB0 * 8); GLD16(gB1 + 32, 12288 + 8192 + uB1 * 8);

    int cur = 0;
    #pragma unroll 3
    for (int k0 = 0; k0 < K; k0 += 32) {
        // fused gate: retire slice s everywhere (6 of s+1 stay in flight)
        if (k0 + 32 < K) asm volatile("s_waitcnt vmcnt(6)\n\ts_barrier" ::: "memory");
        else             asm volatile("s_waitcnt vmcnt(0)\n\ts_barrier" ::: "memory");
        // stage slice s+2 (WAR-safe: that slot's readers done at slice s-1)
        if (k0 + 64 < K) {
            const int ts = (cur + 2 >= 3) ? (cur - 1) : (cur + 2);
            const int tb = ts * 12288;
            GLD16(gA0 + k0 + 64, tb + uA0 * 8); GLD16(gA1 + k0 + 64, tb + uA1 * 8);
            GLD16(gA2 + k0 + 64, tb + uA2 * 8); GLD16(gA3 + k0 + 64, tb + uA3 * 8);
            GLD16(gB0 + k0 + 64, tb + 8192 + uB0 * 8);
            GLD16(gB1 + k0 + 64, tb + 8192 + uB1 * 8);
        }
        const int sa = cur * 12288, sb = sa + 8192;
        half8 af[8], bf[4];
        #pragma unroll
        for (int mf = 0; mf < 8; ++mf) af[mf] = *(const half8*)(const void*)&smem[sa + aoff[mf]];
        #pragma unroll
        for (int nf = 0; nf < 4; ++nf) bf[nf] = *(const half8*)(const void*)&smem[sb + boff[nf]];
        __builtin_amdgcn_s_setprio(1);
        #pragma unroll
        for (int nf = 0; nf < 4; ++nf)
            #pragma unroll
            for (int mf = 0; mf < 8; ++mf)
                acc[mf][nf] = __builtin_amdgcn_mfma_f32_16x16x32_f16(af[mf], bf[nf], acc[mf][nf], 0, 0, 0);
        __builtin_amdgcn_s_setprio(0);
        __builtin_amdgcn_sched_barrier(0);   // keep MFMA+lgkm above next gate
        cur = (cur >= 2) ? 0 : (cur + 1);
    }
    __syncthreads();   // ring dead; smem reused for 256x128 C bounce (64 KB)

    const int nCat0 = n0 + nBase;
    const int region = nCat0 / 768;
    const int colBase = nCat0 - region * 768;

    float badd[4], bmul[4];
    #pragma unroll
    for (int nt = 0; nt < 4; ++nt) {
        int gn = nCat0 + wn + nt * 16 + lr;
        badd[nt] = aBias * biasC[gn];
        bmul[nt] = scaleC[gn];
    }

    // acc -> swizzled 256x128 bounce: chunk cc stored at cc ^ KEY16(row)
    #pragma unroll
    for (int mf = 0; mf < 8; ++mf) {
        #pragma unroll
        for (int nt = 0; nt < 4; ++nt) {
            #pragma unroll
            for (int i = 0; i < 4; ++i) {
                int lrow = wm + mf * 16 + q * 4 + i;
                int lcol = wn + nt * 16 + lr;
                float v = (acc[mf][nt][i] + badd[nt]) * bmul[nt];
                int cc = lcol >> 3, c7 = lcol & 7;
                smem[lrow * 128 + ((cc ^ KEY16(lrow)) << 3) + c7] =
                    __half_as_ushort(__float2half(v));
            }
        }
    }
    __syncthreads();

    if (region < 2) {
        __half* Creg = region ? CK : CQ;
        #pragma unroll
        for (int p = 0; p < 16; ++p) {
            int u = t + p * 256;
            int R = u >> 4, cc = u & 15;
            half8 val = *(const half8*)(const void*)&smem[R * 128 + ((cc ^ KEY16(R)) << 3)];
            *(half8*)(void*)&Creg[(long long)(m0 + R) * 768 + colBase + cc * 8] = val;
        }
    } else {
        long long b = m0 >> 10;
        const int mrow0 = m0 & 1023;
        #pragma unroll
        for (int p = 0; p < 16; ++p) {
            int u = t + p * 256;
            int n = u >> 5, mc = u & 31;
            __align__(16) u16 tmp[8];
            #pragma unroll
            for (int j = 0; j < 8; ++j) {
                int m = mc * 8 + j;
                tmp[j] = smem[m * 128 + ((((n >> 3) ^ KEY16(m))) << 3) + (n & 7)];
            }
            __half* dst = CVt + b * SD + (long long)(colBase + n) * 1024 + mrow0 + mc * 8;
            *(half8*)(void*)dst = *(const half8*)(const void*)tmp;
        }
    }
}

// ===========================================================================
// Attention GEMM (round-4/6 known-good 128^2 form + T5 setprio):
// C = f(A[1024 x K] . B[N x K]^T) per batch, 3-slot ring, counted gate
// vmcnt(4), 48 KB, 3 blocks/CU (independent blocks -> setprio regime).
// MODE 1 (QK^T): v = exp(acc*aAcc) + partial rowsums (no-max softmax).
// MODE 2 (PV):   v = acc * aAcc * invsum[row].
// ===========================================================================
template<int SWIZ, int MODE>
__global__ __launch_bounds__(256, 3)
void gemm_att_k(const __half* __restrict__ A, const __half* __restrict__ B,
                float aAcc, __half* __restrict__ C, int K, int ldc,
                long long sA, long long sB, long long sC,
                int tilesX, int tilesPB, int bpx,
                float* __restrict__ rsp, const float* __restrict__ invsum)
{
    __shared__ __align__(16) u16 smem[24576];   // 48 KB ring; epilogue reuse
    float* sums = (float*)(void*)&smem[16384];  // 8.5 KB, disjoint from qbase

    int nxI, ny;
    long long bz;
    if (SWIZ) {
        int flat = blockIdx.x;
        int xcd = flat & 7;
        int j = flat >> 3;
        int bLocal = j / tilesPB;
        int tt = j - bLocal * tilesPB;
        bz = (long long)(xcd * bpx + bLocal);
        ny = tt / tilesX;
        nxI = tt - ny * tilesX;
    } else {
        nxI = blockIdx.x; ny = blockIdx.y; bz = blockIdx.z;
    }

    const int t = threadIdx.x;
    const int l = t & 63, w = t >> 6;
    const int n0 = nxI * 128;
    const int m0 = ny * 128;
    A += bz * sA; B += bz * sB; C += bz * sC;

    const int wm = (w & 1) * 64, wn = (w >> 1) * 64;

    const int u0 = t, u1 = t + 256;
    const int r0 = u0 >> 2, c0 = (u0 & 3) ^ ((r0 >> 1) & 3);
    const int r1 = u1 >> 2, c1 = (u1 & 3) ^ ((r1 >> 1) & 3);
    const __half* gA0 = A + (long long)(m0 + r0) * K + c0 * 8;
    const __half* gA1 = A + (long long)(m0 + r1) * K + c1 * 8;
    const __half* gB0 = B + (long long)(n0 + r0) * K + c0 * 8;
    const __half* gB1 = B + (long long)(n0 + r1) * K + c1 * 8;

    int aoff[4], boff[4];
    const int kc = l >> 4;
    #pragma unroll
    for (int mt = 0; mt < 4; ++mt) {
        int rr = wm + mt * 16 + (l & 15);
        aoff[mt] = (rr * 4 + (kc ^ ((rr >> 1) & 3))) * 8;
        int rb = wn + mt * 16 + (l & 15);
        boff[mt] = (rb * 4 + (kc ^ ((rb >> 1) & 3))) * 8;
    }

    f32x4 acc[4][4];
    #pragma unroll
    for (int i = 0; i < 4; ++i)
        #pragma unroll
        for (int j = 0; j < 4; ++j)
            acc[i][j] = (f32x4){0.f, 0.f, 0.f, 0.f};

    GLD16(gA0,      u0 * 8);                 GLD16(gA1,      u1 * 8);
    GLD16(gB0,      12288 + u0 * 8);         GLD16(gB1,      12288 + u1 * 8);
    GLD16(gA0 + 32, 4096 + u0 * 8);          GLD16(gA1 + 32, 4096 + u1 * 8);
    GLD16(gB0 + 32, 12288 + 4096 + u0 * 8);  GLD16(gB1 + 32, 12288 + 4096 + u1 * 8);

    int cur = 0;
    #pragma unroll 3
    for (int k0 = 0; k0 < K; k0 += 32) {
        if (k0 + 32 < K) asm volatile("s_waitcnt vmcnt(4)\n\ts_barrier" ::: "memory");
        else             asm volatile("s_waitcnt vmcnt(0)\n\ts_barrier" ::: "memory");
        if (k0 + 64 < K) {
            const int ts = (cur + 2 >= 3) ? (cur - 1) : (cur + 2);
            const int tsa = ts * 4096, tsb = 12288 + ts * 4096;
            GLD16(gA0 + k0 + 64, tsa + u0 * 8);  GLD16(gA1 + k0 + 64, tsa + u1 * 8);
            GLD16(gB0 + k0 + 64, tsb + u0 * 8);  GLD16(gB1 + k0 + 64, tsb + u1 * 8);
        }
        const int sa = cur * 4096, sb = 12288 + cur * 4096;
        half8 af[4], bf[4];
        #pragma unroll
        for (int mt = 0; mt < 4; ++mt) af[mt] = *(const half8*)(const void*)&smem[sa + aoff[mt]];
        #pragma unroll
        for (int nt = 0; nt < 4; ++nt) bf[nt] = *(const half8*)(const void*)&smem[sb + boff[nt]];
        __builtin_amdgcn_s_setprio(1);
        #pragma unroll
        for (int nt = 0; nt < 4; ++nt)
            #pragma unroll
            for (int mt = 0; mt < 4; ++mt)
                acc[mt][nt] = __builtin_amdgcn_mfma_f32_16x16x32_f16(af[mt], bf[nt], acc[mt][nt], 0, 0, 0);
        __builtin_amdgcn_s_setprio(0);
        __builtin_amdgcn_sched_barrier(0);
        cur = (cur >= 2) ? 0 : (cur + 1);
    }
    __syncthreads();   // ring dead; smem reused for epilogue bounce

    // per-thread 1/rowsum values for MODE 2 (broadcast loads, L2-hot)
    float invr[4][4];
    if (MODE == 2) {
        #pragma unroll
        for (int mt = 0; mt < 4; ++mt)
            #pragma unroll
            for (int i = 0; i < 4; ++i)
                invr[mt][i] = invsum[bz * 1024 + m0 + wm + mt * 16 + ((l >> 4) << 2) + i];
    }

    const int qbase = w * 4096;
    #pragma unroll
    for (int mt = 0; mt < 4; ++mt) {
        #pragma unroll
        for (int nt = 0; nt < 4; ++nt) {
            #pragma unroll
            for (int i = 0; i < 4; ++i) {
                int lrow = mt * 16 + ((l >> 4) << 2) + i;
                int lcol = nt * 16 + (l & 15);
                float v;
                if (MODE == 1)      v = __expf(acc[mt][nt][i] * aAcc);
                else                v = acc[mt][nt][i] * aAcc * invr[mt][i];
                int cc = lcol >> 3, c7 = lcol & 7;
                smem[qbase + lrow * 64 + ((cc ^ SW(lrow)) << 3) + c7] =
                    __half_as_ushort(__float2half(v));
            }
        }
    }
    __syncthreads();

    #pragma unroll
    for (int p = 0; p < 8; ++p) {
        int u = t + p * 256;
        int R = u >> 4, cc = u & 15;
        int qb = ((R >> 6) + ((cc >> 3) << 1)) * 4096;
        int lr = R & 63, lcc = cc & 7;
        half8 val = *(const half8*)(const void*)&smem[qb + lr * 64 + ((lcc ^ SW(lr)) << 3)];
        *(half8*)(void*)&C[(long long)(m0 + R) * ldc + n0 + cc * 8] = val;
        if (MODE == 1) {
            float s8 = 0.f;
            #pragma unroll
            for (int j = 0; j < 8; ++j) s8 += (float)val[j];
            sums[R * 17 + cc] = s8;
        }
    }
    if (MODE == 1) {
        __syncthreads();
        if (t < 128) {
            float s = 0.f;
            #pragma unroll
            for (int c = 0; c < 16; ++c) s += sums[t * 17 + c];
            rsp[bz * 8192 + (long long)(m0 + t) * 8 + nxI] = s;
        }
    }
}

// inv[i] = 1 / sum_{c<8} rsp[i*8+c]
__global__ __launch_bounds__(256)
void rowsuminv_k(const float* __restrict__ rsp, float* __restrict__ inv, int n)
{
    int i = blockIdx.x * 256 + threadIdx.x;
    if (i < n) {
        const float* p = rsp + (long long)i * 8;
        float s = ((p[0] + p[1]) + (p[2] + p[3])) + ((p[4] + p[5]) + (p[6] + p[7]));
        inv[i] = 1.0f / s;
    }
}

// ---------------------------------------------------------------------------
__global__ __launch_bounds__(256)
void cvt32to16_k(const float* __restrict__ X, __half* __restrict__ Y)
{
    long long i = ((long long)blockIdx.x * 256 + threadIdx.x) * 4;
    float4 v = *(const float4*)&X[i];
    *(__half2*)&Y[i]     = __floats2half2_rn(v.x, v.y);
    *(__half2*)&Y[i + 2] = __floats2half2_rn(v.z, v.w);
}

// W[l][k][n] fp32 -> Wcat[l][rowOff + n][k] fp16
__global__ __launch_bounds__(256)
void wtrans_k(const float* __restrict__ W, __half* __restrict__ Wt,
              long long ldL, int rowOff)
{
    __shared__ float Ls[64][65];
    const int lyr = blockIdx.z;
    const int k0 = blockIdx.y * 64, n0 = blockIdx.x * 64;
    const float* src = W + (long long)lyr * DD;
    __half* dst = Wt + (long long)lyr * ldL;
    const int t = threadIdx.x;
    #pragma unroll
    for (int p = 0; p < 4; ++p) {
        int u = t + p * 256;
        int r = u >> 4, c4 = (u & 15) * 4;
        float4 v = *(const float4*)&src[(long long)(k0 + r) * D_ + n0 + c4];
        Ls[r][c4] = v.x; Ls[r][c4 + 1] = v.y; Ls[r][c4 + 2] = v.z; Ls[r][c4 + 3] = v.w;
    }
    __syncthreads();
    #pragma unroll
    for (int p = 0; p < 2; ++p) {
        int u = t + p * 256;
        int n = u >> 3, kc8 = (u & 7) * 8;
        __align__(16) u16 tmp[8];
        #pragma unroll
        for (int j = 0; j < 8; ++j) {
            _Float16 h = (_Float16)Ls[kc8 + j][n];
            tmp[j] = *(const u16*)&h;
        }
        *(half8*)(void*)&dst[(long long)(rowOff + n0 + n) * D_ + k0 + kc8] =
            *(const half8*)(const void*)tmp;
    }
}

// build concatenated bias/scale: [l][2304]: Q: (bq, 1) K: (bk, lk) V: (bv, lv)
__global__ __launch_bounds__(256)
void bscat_k(const float* __restrict__ bq, const float* __restrict__ bk,
             const float* __restrict__ bv, const float* __restrict__ lk,
             const float* __restrict__ lv, float* __restrict__ bsb,
             float* __restrict__ bss)
{
    int i = blockIdx.x * 256 + threadIdx.x;
    if (i >= L_ * 2304) return;
    int l = i / 2304, p = i - l * 2304;
    int r = p / 768, c = p - r * 768;
    float b, s;
    if (r == 0)      { b = bq[l * 768 + c]; s = 1.f; }
    else if (r == 1) { b = bk[l * 768 + c]; s = lk[l * 768 + c]; }
    else             { b = bv[l * 768 + c]; s = lv[l * 768 + c]; }
    bsb[i] = b; bss[i] = s;
}

// ---------------- layer-12 row-0 shortcut (fp32) ----------------
__global__ __launch_bounds__(256)
void q0_k(const __half* __restrict__ H16, const __half* __restrict__ Wcat,
          const float* __restrict__ bq, float* __restrict__ q0f, float sig)
{
    const int b = blockIdx.x;
    const int n = blockIdx.y * 256 + threadIdx.x;
    const int t = threadIdx.x;
    __shared__ __half hrow[768];
    const __half* h = H16 + (long long)b * SD;
    hrow[t] = h[t]; hrow[t + 256] = h[t + 256]; hrow[t + 512] = h[t + 512];
    __syncthreads();
    const __half* wr = Wcat + 11LL * LDL + (long long)n * 768;
    float acc = 0.f;
    for (int k = 0; k < 768; ++k) acc += (float)hrow[k] * (float)wr[k];
    q0f[b * 768 + n] = acc + sig * bq[11 * 768 + n];
}

__global__ __launch_bounds__(256)
void s0_k(const float* __restrict__ q0f, const __half* __restrict__ K16,
          float* __restrict__ s0f, int b0, float aQK)
{
    const int z = blockIdx.x;
    const int b = b0 + z;
    const int s = blockIdx.y * 256 + threadIdx.x;
    const int t = threadIdx.x;
    __shared__ float qrow[768];
    qrow[t] = q0f[b * 768 + t];
    qrow[t + 256] = q0f[b * 768 + t + 256];
    qrow[t + 512] = q0f[b * 768 + t + 512];
    __syncthreads();
    const __half* kr = K16 + (long long)z * SD + (long long)s * 768;
    float acc = 0.f;
    for (int k = 0; k < 768; ++k) acc += qrow[k] * (float)kr[k];
    s0f[b * 1024 + s] = acc * aQK;
}

__global__ __launch_bounds__(256)
void sm0_k(float* __restrict__ s0f, int b0)
{
    float* p = s0f + (long long)(b0 + blockIdx.x) * 1024;
    const int t = threadIdx.x;
    float v[4];
    float mx = -1e30f;
    #pragma unroll
    for (int j = 0; j < 4; ++j) { v[j] = p[t + 256 * j]; mx = fmaxf(mx, v[j]); }
    __shared__ float red[256];
    red[t] = mx; __syncthreads();
    for (int s = 128; s > 0; s >>= 1) { if (t < s) red[t] = fmaxf(red[t], red[t + s]); __syncthreads(); }
    mx = red[0];
    __syncthreads();
    float sum = 0.f;
    #pragma unroll
    for (int j = 0; j < 4; ++j) { v[j] = __expf(v[j] - mx); sum += v[j]; }
    red[t] = sum; __syncthreads();
    for (int s = 128; s > 0; s >>= 1) { if (t < s) red[t] += red[t + s]; __syncthreads(); }
    const float inv = 1.0f / red[0];
    __syncthreads();
    #pragma unroll
    for (int j = 0; j < 4; ++j) p[t + 256 * j] = v[j] * inv;
}

__global__ __launch_bounds__(256)
void o0_k(const float* __restrict__ p0f, const __half* __restrict__ Vt16,
          float* __restrict__ o0f, int b0, float invSig)
{
    const int z = blockIdx.x;
    const int b = b0 + z;
    const int d = blockIdx.y * 256 + threadIdx.x;
    const int t = threadIdx.x;
    __shared__ float prow[1024];
    #pragma unroll
    for (int j = 0; j < 4; ++j) prow[t + 256 * j] = p0f[b * 1024 + t + 256 * j];
    __syncthreads();
    const __half* vr = Vt16 + (long long)z * SD + (long long)d * 1024;
    float acc = 0.f;
    for (int s = 0; s < 1024; ++s) acc += prow[s] * (float)vr[s];
    o0f[b * 768 + d] = acc * invSig;
}

__global__ __launch_bounds__(256)
void headf_k(const float* __restrict__ o0f, const float* __restrict__ Wh,
             const float* __restrict__ bh, float* __restrict__ out)
{
    const int b = blockIdx.x;
    const int t = threadIdx.x;
    float s = 0.f;
    for (int d = t; d < 768; d += 256) s += o0f[b * 768 + d] * Wh[d];
    __shared__ float red[256];
    red[t] = s; __syncthreads();
    for (int k = 128; k > 0; k >>= 1) { if (t < k) red[t] += red[t + k]; __syncthreads(); }
    if (t == 0) out[b] = red[0] + bh[0];
}

// ---------------------------------------------------------------------------
extern "C" void kernel_launch(void* const* d_in, const int* in_sizes, int n_in,
                              void* d_out, int out_size, void* d_ws, size_t ws_size,
                              hipStream_t stream)
{
    const float* hs = (const float*)d_in[0];
    const float* Wq = (const float*)d_in[1];
    const float* bq = (const float*)d_in[2];
    const float* Wk = (const float*)d_in[3];
    const float* bk = (const float*)d_in[4];
    const float* Wv = (const float*)d_in[5];
    const float* bv = (const float*)d_in[6];
    const float* lk = (const float*)d_in[7];
    const float* lv = (const float*)d_in[8];
    const float* Wh = (const float*)d_in[9];
    const float* bh = (const float*)d_in[10];
    float* outp = (float*)d_out;

    // ---- workspace layout ----
    __half* H16  = (__half*)d_ws;                    // 32*SD halves
    __half* Wcat = H16 + (long long)B_ * SD;         // 12*LDL halves
    float*  bsb  = (float*)(Wcat + 12LL * LDL);      // 12*2304
    float*  bss  = bsb + 12 * 2304;
    float*  q0f  = bss + 12 * 2304;                  // 32*768
    float*  s0f  = q0f + 32 * 768;                   // 32*1024
    float*  o0f  = s0f + 32 * 1024;                  // 32*768
    float*  rsp  = o0f + 32 * 768;                   // 32*1024*8 partial rowsums
    float*  inv  = rsp + 32LL * 8192;                // 32*1024
    __half* Q16  = (__half*)(inv + 32 * 1024);

    const size_t baseBytes = (size_t)((char*)Q16 - (char*)d_ws);
    const size_t perG = ((size_t)(3 * SD) + (size_t)SS) * 2;   // ~6.8 MB
    long long avail = (long long)ws_size - (long long)baseBytes;
    int G = (avail > 0) ? (int)(avail / perG) : 1;
    if (G >= 32) G = 32; else if (G >= 16) G = 16; else if (G >= 8) G = 8;
    if (G < 1) G = 1;
    __half* K16  = Q16 + (long long)G * SD;
    __half* Vt16 = K16 + (long long)G * SD;
    __half* P16  = Vt16 + (long long)G * SD;

    // ---- converts ----
    cvt32to16_k<<<dim3((int)((B_ * SD) / 1024)), 256, 0, stream>>>(hs, H16);
    wtrans_k<<<dim3(12, 12, 12), 256, 0, stream>>>(Wq, Wcat, LDL, 0);
    wtrans_k<<<dim3(12, 12, 12), 256, 0, stream>>>(Wk, Wcat, LDL, 768);
    wtrans_k<<<dim3(12, 12, 12), 256, 0, stream>>>(Wv, Wcat, LDL, 1536);
    bscat_k<<<dim3((L_ * 2304 + 255) / 256), 256, 0, stream>>>(bq, bk, bv, lk, lv, bsb, bss);

    const float scq = 0.036084391824351615f;   // 1/sqrt(768)
    float sig = 1.f;

    // ---- layers 1..11 (full) ----
    for (int lyr = 0; lyr < L_ - 1; ++lyr) {
        const __half* W = Wcat + (long long)lyr * LDL;
        const float* bb = bsb + lyr * 2304;
        const float* ss = bss + lyr * 2304;
        const float aQK = scq / (sig * sig);

        for (int b0 = 0; b0 < B_; b0 += G) {
            const int nb = (B_ - b0 < G) ? (B_ - b0) : G;
            const __half* hg = H16 + (long long)b0 * SD;

            // fused QKV projection, 256x128 tiles (m-tiles of 256 rows)
            if ((nb & 1) == 0) {
                gemm_qkv_k<1><<<dim3(8 * (nb >> 1) * 18), 256, 0, stream>>>(
                    hg, W, bb, ss, sig, Q16, K16, Vt16, 0, 18, nb >> 1);
            } else {
                gemm_qkv_k<0><<<dim3(nb * 4 * 18), 256, 0, stream>>>(
                    hg, W, bb, ss, sig, Q16, K16, Vt16, 0, 18, 0);
            }

            if ((nb & 7) == 0) {
                gemm_att_k<1, 1><<<dim3(nb * 64), 256, 0, stream>>>(
                    Q16, K16, aQK, P16, 768, 1024, SD, SD, SS, 8, 64, nb >> 3, rsp, nullptr);
            } else {
                gemm_att_k<0, 1><<<dim3(8, 8, nb), 256, 0, stream>>>(
                    Q16, K16, aQK, P16, 768, 1024, SD, SD, SS, 8, 64, 1, rsp, nullptr);
            }

            rowsuminv_k<<<dim3(nb * 4), 256, 0, stream>>>(rsp, inv, nb * 1024);

            if ((nb & 7) == 0) {
                gemm_att_k<1, 2><<<dim3(nb * 48), 256, 0, stream>>>(
                    P16, Vt16, 4.f, H16 + (long long)b0 * SD, 1024, 768, SS, SD, SD,
                    6, 48, nb >> 3, nullptr, inv);
            } else {
                gemm_att_k<0, 2><<<dim3(6, 8, nb), 256, 0, stream>>>(
                    P16, Vt16, 4.f, H16 + (long long)b0 * SD, 1024, 768, SS, SD, SD,
                    6, 48, 1, nullptr, inv);
            }
        }
        sig *= 4.f;
    }

    // ---- layer 12: only row 0 of the output is needed ----
    const float aQK = scq / (sig * sig);
    q0_k<<<dim3(B_, 3), 256, 0, stream>>>(H16, Wcat, bq, q0f, sig);

    for (int b0 = 0; b0 < B_; b0 += G) {
        const int nb = (B_ - b0 < G) ? (B_ - b0) : G;
        const __half* hg = H16 + (long long)b0 * SD;

        // K,V projection only (cat rows 768..2303), region split at 768
        if ((nb & 1) == 0) {
            gemm_qkv_k<1><<<dim3(8 * (nb >> 1) * 12), 256, 0, stream>>>(
                hg, Wcat + 11LL * LDL + 768LL * 768, bsb + 11 * 2304, bss + 11 * 2304,
                sig, K16 /*unused*/, K16, Vt16, 768, 12, nb >> 1);
        } else {
            gemm_qkv_k<0><<<dim3(nb * 4 * 12), 256, 0, stream>>>(
                hg, Wcat + 11LL * LDL + 768LL * 768, bsb + 11 * 2304, bss + 11 * 2304,
                sig, K16 /*unused*/, K16, Vt16, 768, 12, 0);
        }

        s0_k<<<dim3(nb, 4), 256, 0, stream>>>(q0f, K16, s0f, b0, aQK);
        sm0_k<<<dim3(nb), 256, 0, stream>>>(s0f, b0);
        o0_k<<<dim3(nb, 3), 256, 0, stream>>>(s0f, Vt16, o0f, b0, 1.f / sig);
    }

    headf_k<<<dim3(B_), 256, 0, stream>>>(o0f, Wh, bh, outp);
}

// Round 10
// 3215.121 us; speedup vs baseline: 1.3206x; 1.3206x over previous
//
#include <hip/hip_runtime.h>
#include <hip/hip_fp16.h>
#include <math.h>

#define B_ 32
#define S_ 1024
#define D_ 768
#define L_ 12
#define SD 786432LL      // S_*D_ halves per batch
#define SS 1048576LL     // S_*S_ halves per batch
#define DD 589824LL      // D_*D_
#define LDL 1769472LL    // 3*DD halves per layer of Wcat (2304 x 768)

typedef _Float16 half8 __attribute__((ext_vector_type(8)));
typedef float f32x4 __attribute__((ext_vector_type(4)));
typedef unsigned short u16;

// chunk swizzle for the 128^2 att epilogue LDS bounce
#define SW(lr) ((((lr) ^ ((lr) >> 3)) & 7))
// chunk swizzle key for the 256x128 QKV epilogue bounce (round-6 verified)
#define KEY16(r) (((r) ^ ((r) >> 3)) & 15)

// global_load_lds, width 16
#define GLD16(p, o) __builtin_amdgcn_global_load_lds( \
        (const __attribute__((address_space(1))) void*)(p), \
        (__attribute__((address_space(3))) void*)&smem[o], 16, 0, 0)

// ===========================================================================
// Fused QKV projection — ROUND-6 PROVEN FORM (146 us, VGPR 124, no spill).
// 256x128 tile, 4 waves (2M x 2N), wave-tile 128x64, acc[8][4].
// 3-slot ring (A @ s*12288 8192 u16, B +8192; 72 KB), depth-2 prefetch,
// fused counted gate [s_waitcnt vmcnt(6); s_barrier]. 2 blocks/CU.
// REGALLOC CLIFF (rounds 7+9): acc[8][4] ~> 256 VGPR/wave. Both
// __launch_bounds__(256,3) AND s_setprio inside the K-loop push live
// ranges over budget -> accumulator spill to scratch (WRITE_SIZE 147MB ->
// 0.4-1.3GB, 1.6-3.8x slower). Do NOT insert instructions in the K-loop
// or raise the occupancy bound; verify WRITE_SIZE on every touch.
// Epilogue: 256x128 bounce with KEY16 swizzle.
// ===========================================================================
template<int SWIZ>
__global__ __launch_bounds__(256, 2)
void gemm_qkv_k(const __half* __restrict__ A, const __half* __restrict__ Wt,
                const float* __restrict__ biasC, const float* __restrict__ scaleC,
                float aBias,
                __half* __restrict__ CQ, __half* __restrict__ CK, __half* __restrict__ CVt,
                int nBase, int tilesX, int mPerXcd)
{
    __shared__ __align__(16) u16 smem[36864];   // 72 KB ring; 64 KB bounce reuse
    const int K = 768;

    int mIdx, nxI;
    if (SWIZ) {
        const int flat = blockIdx.x;
        const int xcd = flat & 7;
        const int jj = flat >> 3;
        const int mLocal = jj / tilesX;
        nxI = jj - mLocal * tilesX;
        mIdx = xcd * mPerXcd + mLocal;
    } else {
        mIdx = blockIdx.x / tilesX;
        nxI = blockIdx.x - mIdx * tilesX;
    }
    const int m0 = mIdx * 256;
    const int n0 = nxI * 128;

    const int t = threadIdx.x;
    const int l = t & 63, w = t >> 6;
    const int wm = (w & 1) * 128, wn = (w >> 1) * 64;
    const int q = l >> 4, lr = l & 15;

    // staging: A slice 256x32 = 1024 16B-chunks (4/thread), B 128x32 = 512
    // (2/thread). LDS linear in chunk index; global k-chunk pre-swizzled.
    const int uA0 = t, uA1 = t + 256, uA2 = t + 512, uA3 = t + 768;
    const int uB0 = t, uB1 = t + 256;
#define MKA(u) (A + (long long)(m0 + ((u) >> 2)) * K + ((((u) & 3) ^ ((((u) >> 2) >> 1) & 3)) * 8))
#define MKB(u) (Wt + (long long)(n0 + ((u) >> 2)) * K + ((((u) & 3) ^ ((((u) >> 2) >> 1) & 3)) * 8))
    const __half* gA0 = MKA(uA0); const __half* gA1 = MKA(uA1);
    const __half* gA2 = MKA(uA2); const __half* gA3 = MKA(uA3);
    const __half* gB0 = MKB(uB0); const __half* gB1 = MKB(uB1);
#undef MKA
#undef MKB

    int aoff[8], boff[4];
    #pragma unroll
    for (int mf = 0; mf < 8; ++mf) {
        int rr = wm + mf * 16 + lr;
        aoff[mf] = (rr * 4 + (q ^ ((rr >> 1) & 3))) * 8;
    }
    #pragma unroll
    for (int nf = 0; nf < 4; ++nf) {
        int rb = wn + nf * 16 + lr;
        boff[nf] = (rb * 4 + (q ^ ((rb >> 1) & 3))) * 8;
    }

    f32x4 acc[8][4];
    #pragma unroll
    for (int i = 0; i < 8; ++i)
        #pragma unroll
        for (int j = 0; j < 4; ++j)
            acc[i][j] = (f32x4){0.f, 0.f, 0.f, 0.f};

    // prologue: slice 0 -> slot 0, slice 1 -> slot 1 (12 loads, issue order!)
    GLD16(gA0, uA0 * 8); GLD16(gA1, uA1 * 8); GLD16(gA2, uA2 * 8); GLD16(gA3, uA3 * 8);
    GLD16(gB0, 8192 + uB0 * 8); GLD16(gB1, 8192 + uB1 * 8);
    GLD16(gA0 + 32, 12288 + uA0 * 8); GLD16(gA1 + 32, 12288 + uA1 * 8);
    GLD16(gA2 + 32, 12288 + uA2 * 8); GLD16(gA3 + 32, 12288 + uA3 * 8);
    GLD16(gB0 + 32, 12288 + 8192 + uB0 * 8); GLD16(gB1 + 32, 12288 + 8192 + uB1 * 8);

    int cur = 0;
    #pragma unroll 3
    for (int k0 = 0; k0 < K; k0 += 32) {
        // fused gate: retire slice s everywhere (6 of s+1 stay in flight)
        if (k0 + 32 < K) asm volatile("s_waitcnt vmcnt(6)\n\ts_barrier" ::: "memory");
        else             asm volatile("s_waitcnt vmcnt(0)\n\ts_barrier" ::: "memory");
        // stage slice s+2 (WAR-safe: that slot's readers done at slice s-1)
        if (k0 + 64 < K) {
            const int ts = (cur + 2 >= 3) ? (cur - 1) : (cur + 2);
            const int tb = ts * 12288;
            GLD16(gA0 + k0 + 64, tb + uA0 * 8); GLD16(gA1 + k0 + 64, tb + uA1 * 8);
            GLD16(gA2 + k0 + 64, tb + uA2 * 8); GLD16(gA3 + k0 + 64, tb + uA3 * 8);
            GLD16(gB0 + k0 + 64, tb + 8192 + uB0 * 8);
            GLD16(gB1 + k0 + 64, tb + 8192 + uB1 * 8);
        }
        const int sa = cur * 12288, sb = sa + 8192;
        half8 af[8], bf[4];
        #pragma unroll
        for (int mf = 0; mf < 8; ++mf) af[mf] = *(const half8*)(const void*)&smem[sa + aoff[mf]];
        #pragma unroll
        for (int nf = 0; nf < 4; ++nf) bf[nf] = *(const half8*)(const void*)&smem[sb + boff[nf]];
        #pragma unroll
        for (int nf = 0; nf < 4; ++nf)
            #pragma unroll
            for (int mf = 0; mf < 8; ++mf)
                acc[mf][nf] = __builtin_amdgcn_mfma_f32_16x16x32_f16(af[mf], bf[nf], acc[mf][nf], 0, 0, 0);
        __builtin_amdgcn_sched_barrier(0);   // keep MFMA+lgkm above next gate
        cur = (cur >= 2) ? 0 : (cur + 1);
    }
    __syncthreads();   // ring dead; smem reused for 256x128 C bounce (64 KB)

    const int nCat0 = n0 + nBase;
    const int region = nCat0 / 768;
    const int colBase = nCat0 - region * 768;

    float badd[4], bmul[4];
    #pragma unroll
    for (int nt = 0; nt < 4; ++nt) {
        int gn = nCat0 + wn + nt * 16 + lr;
        badd[nt] = aBias * biasC[gn];
        bmul[nt] = scaleC[gn];
    }

    // acc -> swizzled 256x128 bounce: chunk cc stored at cc ^ KEY16(row)
    #pragma unroll
    for (int mf = 0; mf < 8; ++mf) {
        #pragma unroll
        for (int nt = 0; nt < 4; ++nt) {
            #pragma unroll
            for (int i = 0; i < 4; ++i) {
                int lrow = wm + mf * 16 + q * 4 + i;
                int lcol = wn + nt * 16 + lr;
                float v = (acc[mf][nt][i] + badd[nt]) * bmul[nt];
                int cc = lcol >> 3, c7 = lcol & 7;
                smem[lrow * 128 + ((cc ^ KEY16(lrow)) << 3) + c7] =
                    __half_as_ushort(__float2half(v));
            }
        }
    }
    __syncthreads();

    if (region < 2) {
        __half* Creg = region ? CK : CQ;
        #pragma unroll
        for (int p = 0; p < 16; ++p) {
            int u = t + p * 256;
            int R = u >> 4, cc = u & 15;
            half8 val = *(const half8*)(const void*)&smem[R * 128 + ((cc ^ KEY16(R)) << 3)];
            *(half8*)(void*)&Creg[(long long)(m0 + R) * 768 + colBase + cc * 8] = val;
        }
    } else {
        long long b = m0 >> 10;
        const int mrow0 = m0 & 1023;
        #pragma unroll
        for (int p = 0; p < 16; ++p) {
            int u = t + p * 256;
            int n = u >> 5, mc = u & 31;
            __align__(16) u16 tmp[8];
            #pragma unroll
            for (int j = 0; j < 8; ++j) {
                int m = mc * 8 + j;
                tmp[j] = smem[m * 128 + ((((n >> 3) ^ KEY16(m))) << 3) + (n & 7)];
            }
            __half* dst = CVt + b * SD + (long long)(colBase + n) * 1024 + mrow0 + mc * 8;
            *(half8*)(void*)dst = *(const half8*)(const void*)tmp;
        }
    }
}

// ===========================================================================
// Attention GEMM (round-4/6 known-good 128^2 form): C = f(A . B^T) per
// batch, 3-slot ring, counted gate vmcnt(4), 48 KB, 3 blocks/CU.
// MODE 1 (QK^T): v = exp(acc*aAcc) + partial rowsums (no-max softmax).
// MODE 2 (PV):   v = acc * aAcc * invsum[row].
// ===========================================================================
template<int SWIZ, int MODE>
__global__ __launch_bounds__(256, 3)
void gemm_att_k(const __half* __restrict__ A, const __half* __restrict__ B,
                float aAcc, __half* __restrict__ C, int K, int ldc,
                long long sA, long long sB, long long sC,
                int tilesX, int tilesPB, int bpx,
                float* __restrict__ rsp, const float* __restrict__ invsum)
{
    __shared__ __align__(16) u16 smem[24576];   // 48 KB ring; epilogue reuse
    float* sums = (float*)(void*)&smem[16384];  // 8.5 KB, disjoint from qbase

    int nxI, ny;
    long long bz;
    if (SWIZ) {
        int flat = blockIdx.x;
        int xcd = flat & 7;
        int j = flat >> 3;
        int bLocal = j / tilesPB;
        int tt = j - bLocal * tilesPB;
        bz = (long long)(xcd * bpx + bLocal);
        ny = tt / tilesX;
        nxI = tt - ny * tilesX;
    } else {
        nxI = blockIdx.x; ny = blockIdx.y; bz = blockIdx.z;
    }

    const int t = threadIdx.x;
    const int l = t & 63, w = t >> 6;
    const int n0 = nxI * 128;
    const int m0 = ny * 128;
    A += bz * sA; B += bz * sB; C += bz * sC;

    const int wm = (w & 1) * 64, wn = (w >> 1) * 64;

    const int u0 = t, u1 = t + 256;
    const int r0 = u0 >> 2, c0 = (u0 & 3) ^ ((r0 >> 1) & 3);
    const int r1 = u1 >> 2, c1 = (u1 & 3) ^ ((r1 >> 1) & 3);
    const __half* gA0 = A + (long long)(m0 + r0) * K + c0 * 8;
    const __half* gA1 = A + (long long)(m0 + r1) * K + c1 * 8;
    const __half* gB0 = B + (long long)(n0 + r0) * K + c0 * 8;
    const __half* gB1 = B + (long long)(n0 + r1) * K + c1 * 8;

    int aoff[4], boff[4];
    const int kc = l >> 4;
    #pragma unroll
    for (int mt = 0; mt < 4; ++mt) {
        int rr = wm + mt * 16 + (l & 15);
        aoff[mt] = (rr * 4 + (kc ^ ((rr >> 1) & 3))) * 8;
        int rb = wn + mt * 16 + (l & 15);
        boff[mt] = (rb * 4 + (kc ^ ((rb >> 1) & 3))) * 8;
    }

    f32x4 acc[4][4];
    #pragma unroll
    for (int i = 0; i < 4; ++i)
        #pragma unroll
        for (int j = 0; j < 4; ++j)
            acc[i][j] = (f32x4){0.f, 0.f, 0.f, 0.f};

    GLD16(gA0,      u0 * 8);                 GLD16(gA1,      u1 * 8);
    GLD16(gB0,      12288 + u0 * 8);         GLD16(gB1,      12288 + u1 * 8);
    GLD16(gA0 + 32, 4096 + u0 * 8);          GLD16(gA1 + 32, 4096 + u1 * 8);
    GLD16(gB0 + 32, 12288 + 4096 + u0 * 8);  GLD16(gB1 + 32, 12288 + 4096 + u1 * 8);

    int cur = 0;
    #pragma unroll 3
    for (int k0 = 0; k0 < K; k0 += 32) {
        if (k0 + 32 < K) asm volatile("s_waitcnt vmcnt(4)\n\ts_barrier" ::: "memory");
        else             asm volatile("s_waitcnt vmcnt(0)\n\ts_barrier" ::: "memory");
        if (k0 + 64 < K) {
            const int ts = (cur + 2 >= 3) ? (cur - 1) : (cur + 2);
            const int tsa = ts * 4096, tsb = 12288 + ts * 4096;
            GLD16(gA0 + k0 + 64, tsa + u0 * 8);  GLD16(gA1 + k0 + 64, tsa + u1 * 8);
            GLD16(gB0 + k0 + 64, tsb + u0 * 8);  GLD16(gB1 + k0 + 64, tsb + u1 * 8);
        }
        const int sa = cur * 4096, sb = 12288 + cur * 4096;
        half8 af[4], bf[4];
        #pragma unroll
        for (int mt = 0; mt < 4; ++mt) af[mt] = *(const half8*)(const void*)&smem[sa + aoff[mt]];
        #pragma unroll
        for (int nt = 0; nt < 4; ++nt) bf[nt] = *(const half8*)(const void*)&smem[sb + boff[nt]];
        #pragma unroll
        for (int nt = 0; nt < 4; ++nt)
            #pragma unroll
            for (int mt = 0; mt < 4; ++mt)
                acc[mt][nt] = __builtin_amdgcn_mfma_f32_16x16x32_f16(af[mt], bf[nt], acc[mt][nt], 0, 0, 0);
        __builtin_amdgcn_sched_barrier(0);
        cur = (cur >= 2) ? 0 : (cur + 1);
    }
    __syncthreads();   // ring dead; smem reused for epilogue bounce

    // per-thread 1/rowsum values for MODE 2 (broadcast loads, L2-hot)
    float invr[4][4];
    if (MODE == 2) {
        #pragma unroll
        for (int mt = 0; mt < 4; ++mt)
            #pragma unroll
            for (int i = 0; i < 4; ++i)
                invr[mt][i] = invsum[bz * 1024 + m0 + wm + mt * 16 + ((l >> 4) << 2) + i];
    }

    const int qbase = w * 4096;
    #pragma unroll
    for (int mt = 0; mt < 4; ++mt) {
        #pragma unroll
        for (int nt = 0; nt < 4; ++nt) {
            #pragma unroll
            for (int i = 0; i < 4; ++i) {
                int lrow = mt * 16 + ((l >> 4) << 2) + i;
                int lcol = nt * 16 + (l & 15);
                float v;
                if (MODE == 1)      v = __expf(acc[mt][nt][i] * aAcc);
                else                v = acc[mt][nt][i] * aAcc * invr[mt][i];
                int cc = lcol >> 3, c7 = lcol & 7;
                smem[qbase + lrow * 64 + ((cc ^ SW(lrow)) << 3) + c7] =
                    __half_as_ushort(__float2half(v));
            }
        }
    }
    __syncthreads();

    #pragma unroll
    for (int p = 0; p < 8; ++p) {
        int u = t + p * 256;
        int R = u >> 4, cc = u & 15;
        int qb = ((R >> 6) + ((cc >> 3) << 1)) * 4096;
        int lr = R & 63, lcc = cc & 7;
        half8 val = *(const half8*)(const void*)&smem[qb + lr * 64 + ((lcc ^ SW(lr)) << 3)];
        *(half8*)(void*)&C[(long long)(m0 + R) * ldc + n0 + cc * 8] = val;
        if (MODE == 1) {
            float s8 = 0.f;
            #pragma unroll
            for (int j = 0; j < 8; ++j) s8 += (float)val[j];
            sums[R * 17 + cc] = s8;
        }
    }
    if (MODE == 1) {
        __syncthreads();
        if (t < 128) {
            float s = 0.f;
            #pragma unroll
            for (int c = 0; c < 16; ++c) s += sums[t * 17 + c];
            rsp[bz * 8192 + (long long)(m0 + t) * 8 + nxI] = s;
        }
    }
}

// inv[i] = 1 / sum_{c<8} rsp[i*8+c]
__global__ __launch_bounds__(256)
void rowsuminv_k(const float* __restrict__ rsp, float* __restrict__ inv, int n)
{
    int i = blockIdx.x * 256 + threadIdx.x;
    if (i < n) {
        const float* p = rsp + (long long)i * 8;
        float s = ((p[0] + p[1]) + (p[2] + p[3])) + ((p[4] + p[5]) + (p[6] + p[7]));
        inv[i] = 1.0f / s;
    }
}

// ---------------------------------------------------------------------------
__global__ __launch_bounds__(256)
void cvt32to16_k(const float* __restrict__ X, __half* __restrict__ Y)
{
    long long i = ((long long)blockIdx.x * 256 + threadIdx.x) * 4;
    float4 v = *(const float4*)&X[i];
    *(__half2*)&Y[i]     = __floats2half2_rn(v.x, v.y);
    *(__half2*)&Y[i + 2] = __floats2half2_rn(v.z, v.w);
}

// W[l][k][n] fp32 -> Wcat[l][rowOff + n][k] fp16
__global__ __launch_bounds__(256)
void wtrans_k(const float* __restrict__ W, __half* __restrict__ Wt,
              long long ldL, int rowOff)
{
    __shared__ float Ls[64][65];
    const int lyr = blockIdx.z;
    const int k0 = blockIdx.y * 64, n0 = blockIdx.x * 64;
    const float* src = W + (long long)lyr * DD;
    __half* dst = Wt + (long long)lyr * ldL;
    const int t = threadIdx.x;
    #pragma unroll
    for (int p = 0; p < 4; ++p) {
        int u = t + p * 256;
        int r = u >> 4, c4 = (u & 15) * 4;
        float4 v = *(const float4*)&src[(long long)(k0 + r) * D_ + n0 + c4];
        Ls[r][c4] = v.x; Ls[r][c4 + 1] = v.y; Ls[r][c4 + 2] = v.z; Ls[r][c4 + 3] = v.w;
    }
    __syncthreads();
    #pragma unroll
    for (int p = 0; p < 2; ++p) {
        int u = t + p * 256;
        int n = u >> 3, kc8 = (u & 7) * 8;
        __align__(16) u16 tmp[8];
        #pragma unroll
        for (int j = 0; j < 8; ++j) {
            _Float16 h = (_Float16)Ls[kc8 + j][n];
            tmp[j] = *(const u16*)&h;
        }
        *(half8*)(void*)&dst[(long long)(rowOff + n0 + n) * D_ + k0 + kc8] =
            *(const half8*)(const void*)tmp;
    }
}

// build concatenated bias/scale: [l][2304]: Q: (bq, 1) K: (bk, lk) V: (bv, lv)
__global__ __launch_bounds__(256)
void bscat_k(const float* __restrict__ bq, const float* __restrict__ bk,
             const float* __restrict__ bv, const float* __restrict__ lk,
             const float* __restrict__ lv, float* __restrict__ bsb,
             float* __restrict__ bss)
{
    int i = blockIdx.x * 256 + threadIdx.x;
    if (i >= L_ * 2304) return;
    int l = i / 2304, p = i - l * 2304;
    int r = p / 768, c = p - r * 768;
    float b, s;
    if (r == 0)      { b = bq[l * 768 + c]; s = 1.f; }
    else if (r == 1) { b = bk[l * 768 + c]; s = lk[l * 768 + c]; }
    else             { b = bv[l * 768 + c]; s = lv[l * 768 + c]; }
    bsb[i] = b; bss[i] = s;
}

// ---------------- layer-12 row-0 shortcut (fp32) ----------------
__global__ __launch_bounds__(256)
void q0_k(const __half* __restrict__ H16, const __half* __restrict__ Wcat,
          const float* __restrict__ bq, float* __restrict__ q0f, float sig)
{
    const int b = blockIdx.x;
    const int n = blockIdx.y * 256 + threadIdx.x;
    const int t = threadIdx.x;
    __shared__ __half hrow[768];
    const __half* h = H16 + (long long)b * SD;
    hrow[t] = h[t]; hrow[t + 256] = h[t + 256]; hrow[t + 512] = h[t + 512];
    __syncthreads();
    const __half* wr = Wcat + 11LL * LDL + (long long)n * 768;
    float acc = 0.f;
    for (int k = 0; k < 768; ++k) acc += (float)hrow[k] * (float)wr[k];
    q0f[b * 768 + n] = acc + sig * bq[11 * 768 + n];
}

__global__ __launch_bounds__(256)
void s0_k(const float* __restrict__ q0f, const __half* __restrict__ K16,
          float* __restrict__ s0f, int b0, float aQK)
{
    const int z = blockIdx.x;
    const int b = b0 + z;
    const int s = blockIdx.y * 256 + threadIdx.x;
    const int t = threadIdx.x;
    __shared__ float qrow[768];
    qrow[t] = q0f[b * 768 + t];
    qrow[t + 256] = q0f[b * 768 + t + 256];
    qrow[t + 512] = q0f[b * 768 + t + 512];
    __syncthreads();
    const __half* kr = K16 + (long long)z * SD + (long long)s * 768;
    float acc = 0.f;
    for (int k = 0; k < 768; ++k) acc += qrow[k] * (float)kr[k];
    s0f[b * 1024 + s] = acc * aQK;
}

__global__ __launch_bounds__(256)
void sm0_k(float* __restrict__ s0f, int b0)
{
    float* p = s0f + (long long)(b0 + blockIdx.x) * 1024;
    const int t = threadIdx.x;
    float v[4];
    float mx = -1e30f;
    #pragma unroll
    for (int j = 0; j < 4; ++j) { v[j] = p[t + 256 * j]; mx = fmaxf(mx, v[j]); }
    __shared__ float red[256];
    red[t] = mx; __syncthreads();
    for (int s = 128; s > 0; s >>= 1) { if (t < s) red[t] = fmaxf(red[t], red[t + s]); __syncthreads(); }
    mx = red[0];
    __syncthreads();
    float sum = 0.f;
    #pragma unroll
    for (int j = 0; j < 4; ++j) { v[j] = __expf(v[j] - mx); sum += v[j]; }
    red[t] = sum; __syncthreads();
    for (int s = 128; s > 0; s >>= 1) { if (t < s) red[t] += red[t + s]; __syncthreads(); }
    const float inv = 1.0f / red[0];
    __syncthreads();
    #pragma unroll
    for (int j = 0; j < 4; ++j) p[t + 256 * j] = v[j] * inv;
}

__global__ __launch_bounds__(256)
void o0_k(const float* __restrict__ p0f, const __half* __restrict__ Vt16,
          float* __restrict__ o0f, int b0, float invSig)
{
    const int z = blockIdx.x;
    const int b = b0 + z;
    const int d = blockIdx.y * 256 + threadIdx.x;
    const int t = threadIdx.x;
    __shared__ float prow[1024];
    #pragma unroll
    for (int j = 0; j < 4; ++j) prow[t + 256 * j] = p0f[b * 1024 + t + 256 * j];
    __syncthreads();
    const __half* vr = Vt16 + (long long)z * SD + (long long)d * 1024;
    float acc = 0.f;
    for (int s = 0; s < 1024; ++s) acc += prow[s] * (float)vr[s];
    o0f[b * 768 + d] = acc * invSig;
}

__global__ __launch_bounds__(256)
void headf_k(const float* __restrict__ o0f, const float* __restrict__ Wh,
             const float* __restrict__ bh, float* __restrict__ out)
{
    const int b = blockIdx.x;
    const int t = threadIdx.x;
    float s = 0.f;
    for (int d = t; d < 768; d += 256) s += o0f[b * 768 + d] * Wh[d];
    __shared__ float red[256];
    red[t] = s; __syncthreads();
    for (int k = 128; k > 0; k >>= 1) { if (t < k) red[t] += red[t + k]; __syncthreads(); }
    if (t == 0) out[b] = red[0] + bh[0];
}

// ---------------------------------------------------------------------------
extern "C" void kernel_launch(void* const* d_in, const int* in_sizes, int n_in,
                              void* d_out, int out_size, void* d_ws, size_t ws_size,
                              hipStream_t stream)
{
    const float* hs = (const float*)d_in[0];
    const float* Wq = (const float*)d_in[1];
    const float* bq = (const float*)d_in[2];
    const float* Wk = (const float*)d_in[3];
    const float* bk = (const float*)d_in[4];
    const float* Wv = (const float*)d_in[5];
    const float* bv = (const float*)d_in[6];
    const float* lk = (const float*)d_in[7];
    const float* lv = (const float*)d_in[8];
    const float* Wh = (const float*)d_in[9];
    const float* bh = (const float*)d_in[10];
    float* outp = (float*)d_out;

    // ---- workspace layout ----
    __half* H16  = (__half*)d_ws;                    // 32*SD halves
    __half* Wcat = H16 + (long long)B_ * SD;         // 12*LDL halves
    float*  bsb  = (float*)(Wcat + 12LL * LDL);      // 12*2304
    float*  bss  = bsb + 12 * 2304;
    float*  q0f  = bss + 12 * 2304;                  // 32*768
    float*  s0f  = q0f + 32 * 768;                   // 32*1024
    float*  o0f  = s0f + 32 * 1024;                  // 32*768
    float*  rsp  = o0f + 32 * 768;                   // 32*1024*8 partial rowsums
    float*  inv  = rsp + 32LL * 8192;                // 32*1024
    __half* Q16  = (__half*)(inv + 32 * 1024);

    const size_t baseBytes = (size_t)((char*)Q16 - (char*)d_ws);
    const size_t perG = ((size_t)(3 * SD) + (size_t)SS) * 2;   // ~6.8 MB
    long long avail = (long long)ws_size - (long long)baseBytes;
    int G = (avail > 0) ? (int)(avail / perG) : 1;
    if (G >= 32) G = 32; else if (G >= 16) G = 16; else if (G >= 8) G = 8;
    if (G < 1) G = 1;
    __half* K16  = Q16 + (long long)G * SD;
    __half* Vt16 = K16 + (long long)G * SD;
    __half* P16  = Vt16 + (long long)G * SD;

    // ---- converts ----
    cvt32to16_k<<<dim3((int)((B_ * SD) / 1024)), 256, 0, stream>>>(hs, H16);
    wtrans_k<<<dim3(12, 12, 12), 256, 0, stream>>>(Wq, Wcat, LDL, 0);
    wtrans_k<<<dim3(12, 12, 12), 256, 0, stream>>>(Wk, Wcat, LDL, 768);
    wtrans_k<<<dim3(12, 12, 12), 256, 0, stream>>>(Wv, Wcat, LDL, 1536);
    bscat_k<<<dim3((L_ * 2304 + 255) / 256), 256, 0, stream>>>(bq, bk, bv, lk, lv, bsb, bss);

    const float scq = 0.036084391824351615f;   // 1/sqrt(768)
    float sig = 1.f;

    // ---- layers 1..11 (full) ----
    for (int lyr = 0; lyr < L_ - 1; ++lyr) {
        const __half* W = Wcat + (long long)lyr * LDL;
        const float* bb = bsb + lyr * 2304;
        const float* ss = bss + lyr * 2304;
        const float aQK = scq / (sig * sig);

        for (int b0 = 0; b0 < B_; b0 += G) {
            const int nb = (B_ - b0 < G) ? (B_ - b0) : G;
            const __half* hg = H16 + (long long)b0 * SD;

            // fused QKV projection, 256x128 tiles (m-tiles of 256 rows)
            if ((nb & 1) == 0) {
                gemm_qkv_k<1><<<dim3(8 * (nb >> 1) * 18), 256, 0, stream>>>(
                    hg, W, bb, ss, sig, Q16, K16, Vt16, 0, 18, nb >> 1);
            } else {
                gemm_qkv_k<0><<<dim3(nb * 4 * 18), 256, 0, stream>>>(
                    hg, W, bb, ss, sig, Q16, K16, Vt16, 0, 18, 0);
            }

            if ((nb & 7) == 0) {
                gemm_att_k<1, 1><<<dim3(nb * 64), 256, 0, stream>>>(
                    Q16, K16, aQK, P16, 768, 1024, SD, SD, SS, 8, 64, nb >> 3, rsp, nullptr);
            } else {
                gemm_att_k<0, 1><<<dim3(8, 8, nb), 256, 0, stream>>>(
                    Q16, K16, aQK, P16, 768, 1024, SD, SD, SS, 8, 64, 1, rsp, nullptr);
            }

            rowsuminv_k<<<dim3(nb * 4), 256, 0, stream>>>(rsp, inv, nb * 1024);

            if ((nb & 7) == 0) {
                gemm_att_k<1, 2><<<dim3(nb * 48), 256, 0, stream>>>(
                    P16, Vt16, 4.f, H16 + (long long)b0 * SD, 1024, 768, SS, SD, SD,
                    6, 48, nb >> 3, nullptr, inv);
            } else {
                gemm_att_k<0, 2><<<dim3(6, 8, nb), 256, 0, stream>>>(
                    P16, Vt16, 4.f, H16 + (long long)b0 * SD, 1024, 768, SS, SD, SD,
                    6, 48, 1, nullptr, inv);
            }
        }
        sig *= 4.f;
    }

    // ---- layer 12: only row 0 of the output is needed ----
    const float aQK = scq / (sig * sig);
    q0_k<<<dim3(B_, 3), 256, 0, stream>>>(H16, Wcat, bq, q0f, sig);

    for (int b0 = 0; b0 < B_; b0 += G) {
        const int nb = (B_ - b0 < G) ? (B_ - b0) : G;
        const __half* hg = H16 + (long long)b0 * SD;

        // K,V projection only (cat rows 768..2303), region split at 768
        if ((nb & 1) == 0) {
            gemm_qkv_k<1><<<dim3(8 * (nb >> 1) * 12), 256, 0, stream>>>(
                hg, Wcat + 11LL * LDL + 768LL * 768, bsb + 11 * 2304, bss + 11 * 2304,
                sig, K16 /*unused*/, K16, Vt16, 768, 12, nb >> 1);
        } else {
            gemm_qkv_k<0><<<dim3(nb * 4 * 12), 256, 0, stream>>>(
                hg, Wcat + 11LL * LDL + 768LL * 768, bsb + 11 * 2304, bss + 11 * 2304,
                sig, K16 /*unused*/, K16, Vt16, 768, 12, 0);
        }

        s0_k<<<dim3(nb, 4), 256, 0, stream>>>(q0f, K16, s0f, b0, aQK);
        sm0_k<<<dim3(nb), 256, 0, stream>>>(s0f, b0);
        o0_k<<<dim3(nb, 3), 256, 0, stream>>>(s0f, Vt16, o0f, b0, 1.f / sig);
    }

    headf_k<<<dim3(B_), 256, 0, stream>>>(o0f, Wh, bh, outp);
}